// Round 15
// baseline (282.920 us; speedup 1.0000x reference)
//
#include <hip/hip_runtime.h>
#include <math.h>

namespace {
constexpr int CDIM   = 128;
constexpr int KCODES = 1024;
constexpr int HWSZ   = 4096;   // 64*64
constexpr int BATCH  = 16;
constexpr int NPOS   = BATCH * HWSZ;            // 65536
constexpr int P      = 256;                     // positions per block
constexpr int NWAVES = 16;                      // 1024 threads
constexpr int KPW    = KCODES / NWAVES;         // 64 codes per wave
constexpr int KT     = 8;                       // codes per inner tile
constexpr int THREADS = 1024;
constexpr size_t QELEMS   = (size_t)BATCH * CDIM * HWSZ;   // 8388608
constexpr size_t IDX_OFF  = QELEMS;                        // float32 elements
constexpr size_t LOSS_OFF = IDX_OFF + (size_t)NPOS;        // 8454144
constexpr size_t PERP_OFF = LOSS_OFF + 1;
// d_ws float-element offsets
constexpr int WS_C2   = 0;      // [0,1024)   float ||c_k||^2 (numpy-bit-exact)
constexpr int WS_HIST = 1024;   // [1024,2048) uint  usage counts
constexpr int WS_LOSS = 2048;   // [2048]     float sum ||z-q||^2
constexpr float INV_TOTAL = 1.0f / (float)QELEMS;
constexpr float INV_NPOS  = 1.0f / (float)NPOS;
}

// Bit-exact replica of numpy pairwise_sum for n=128 contiguous float32 applied
// to elementwise squares: 8 accumulator chains (stride 8), sequential within a
// chain, combined ((r0+r1)+(r2+r3))+((r4+r5)+(r6+r7)). __f*_rn forbids fma
// contraction (numpy multiplies into a temp, then adds — never fused).
__device__ __forceinline__ float np_sumsq_128(const float* v) {
    float r[8];
    #pragma unroll
    for (int j = 0; j < 8; ++j) r[j] = __fmul_rn(v[j], v[j]);
    #pragma unroll
    for (int i = 8; i < 128; i += 8) {
        #pragma unroll
        for (int j = 0; j < 8; ++j)
            r[j] = __fadd_rn(r[j], __fmul_rn(v[i + j], v[i + j]));
    }
    const float s01 = __fadd_rn(r[0], r[1]);
    const float s23 = __fadd_rn(r[2], r[3]);
    const float s45 = __fadd_rn(r[4], r[5]);
    const float s67 = __fadd_rn(r[6], r[7]);
    return __fadd_rn(__fadd_rn(s01, s23), __fadd_rn(s45, s67));
}

// ---- pass 0: codebook norms (numpy-bit-exact) + zero accumulators ----------
__global__ __launch_bounds__(256) void vq_prep(const float* __restrict__ cb,
                                               float* __restrict__ ws) {
    const int k = blockIdx.x * 256 + threadIdx.x;   // 0..1023
    const float* row = cb + (size_t)k * CDIM;
    float rr[CDIM];
    #pragma unroll
    for (int c = 0; c < CDIM; ++c) rr[c] = row[c];
    ws[WS_C2 + k] = np_sumsq_128(rr);
    ((unsigned int*)ws)[WS_HIST + k] = 0u;
    if (k == 0) ws[WS_LOSS] = 0.0f;
}

// ---- pass 1: codes via SGPR, z via LDS, 1024-thread blocks ------------------
// Round 15. sQC line throughput backed out of R12/R13/R14: 30/26.5/25.2
// cy per 64B line per CU — invariant across configs. The SGPR design was
// SMEM-THROUGHPUT-bound: 512 blocks x 512KB codebook stream = 256MB ->
// ~184us floor (R13/14 = floor + overheads). Traffic = codebook x nblocks,
// so HALVE THE BLOCKS: P=256, 1024 threads, 16 waves x 64-code strip, grid
// 256 = one block per CU, one generation. SMEM 128MB -> ~92us; DS ~82us;
// both under the 109us FMA floor -> FMA-bound for the first time. 4 waves/
// SIMD (VGPR ~52-70 <= 128 cap). Inner body byte-identical to R12's proven
// compile (4 pos/lane x 8 codes, cv[8]=32 SGPRs). LDS 154.5KB: zt 128K +
// bdls 16K + bkls(ushort) 8K + z2s/wkls/red. WRITE_SIZE = spill tripwire.
// Bit-exactness: per (pos,code) ONE ascending-c fma chain (c,c+1,c+2,c+3 in
// quad, quads ascend); z2 numpy pairwise 8-chain; d = fl(fl(z2-2zc)+c2);
// strict-< with ascending k (j ascends in tile, tiles ascend, 16 contiguous
// ascending strips); cross-wave lexicographic (d,k) min == np.argmin
// first-index tie-break over disjoint subsets.
__global__ __launch_bounds__(1024, 1) void vq_main(const float* __restrict__ z,
                                                   const float* __restrict__ cb,
                                                   float* __restrict__ ws,
                                                   float* __restrict__ out) {
    __shared__ __align__(16) float zt[CDIM][P];     // 128 KB  zt[c][p]
    __shared__ float z2s[P];                        // 1 KB
    __shared__ float bdls[NWAVES][P];               // 16 KB  per-wave best_d
    __shared__ unsigned short bkls[NWAVES][P];      // 8 KB   per-wave best_k
    __shared__ unsigned short wkls[P];              // 512 B  winning code
    __shared__ float red[P];                        // 1 KB   (total ~154.5 KB)

    const int tid   = threadIdx.x;
    const int nbase = blockIdx.x * P;
    const int b     = nbase >> 12;          // 4096 positions per batch image
    const int hw0   = nbase & (HWSZ - 1);   // 256-aligned
    const float* zb = z + (size_t)b * CDIM * HWSZ + hw0;

    // ---- stage z strip: zt[c][p] = z[b][c][hw0+p] (coalesced) --------------
    #pragma unroll
    for (int i = 0; i < (CDIM * P / 4) / THREADS; ++i) {   // 8 iters
        const int linear = i * THREADS + tid;              // 0..8191
        const int c  = linear >> 6;                        // 64 float4 per row
        const int p4 = (linear & 63) * 4;
        *(float4*)&zt[c][p4] = *(const float4*)(zb + (size_t)c * HWSZ + p4);
    }
    __syncthreads();

    // ---- z2 per position: numpy pairwise 8-chain, streamed from LDS --------
    if (tid < P) {
        const int p = tid;
        float r[8];
        #pragma unroll
        for (int j = 0; j < 8; ++j) {
            const float x = zt[j][p];
            r[j] = __fmul_rn(x, x);
        }
        #pragma unroll
        for (int i = 8; i < CDIM; i += 8) {
            #pragma unroll
            for (int j = 0; j < 8; ++j) {
                const float x = zt[i + j][p];
                r[j] = __fadd_rn(r[j], __fmul_rn(x, x));
            }
        }
        const float s01 = __fadd_rn(r[0], r[1]);
        const float s23 = __fadd_rn(r[2], r[3]);
        const float s45 = __fadd_rn(r[4], r[5]);
        const float s67 = __fadd_rn(r[6], r[7]);
        z2s[p] = __fadd_rn(__fadd_rn(s01, s23), __fadd_rn(s45, s67));
    }
    __syncthreads();

    const int lane = tid & 63;
    const int p0   = lane * 4;              // each lane owns 4 positions
    // readfirstlane makes the wave id PROVABLY scalar -> all code addresses
    // derived from it are scalar -> compiler emits s_load (SGPR destination).
    const int wid  = __builtin_amdgcn_readfirstlane(tid >> 6);
    const int kw   = wid * KPW;             // wave's contiguous code strip
    const float* c2g = ws + WS_C2;

    float z2r[4];
    #pragma unroll
    for (int i = 0; i < 4; ++i) z2r[i] = z2s[p0 + i];

    float bestd[4] = {INFINITY, INFINITY, INFINITY, INFINITY};
    int   bestk[4] = {0, 0, 0, 0};

    // ---- main loop: NO barriers; codes via scalar loads --------------------
    for (int ht = 0; ht < KPW / KT; ++ht) {        // 8 tiles of 8 codes
        const int kb = kw + ht * KT;
        const float* ctile = cb + (size_t)kb * CDIM;  // scalar base

        float a[4][KT];
        #pragma unroll
        for (int i = 0; i < 4; ++i)
            #pragma unroll
            for (int j = 0; j < KT; ++j) a[i][j] = 0.0f;

        #pragma unroll 2
        for (int c4 = 0; c4 < CDIM / 4; ++c4) {
            const int c = c4 * 4;
            const float4 zv0 = *(const float4*)&zt[c + 0][p0];
            const float4 zv1 = *(const float4*)&zt[c + 1][p0];
            const float4 zv2 = *(const float4*)&zt[c + 2][p0];
            const float4 zv3 = *(const float4*)&zt[c + 3][p0];
            float4 cv[KT];  // scalar (SGPR) values, uniform across the wave
            #pragma unroll
            for (int j = 0; j < KT; ++j)
                cv[j] = *(const float4*)(ctile + (size_t)j * CDIM + c);
            #pragma unroll
            for (int j = 0; j < KT; ++j) {
                a[0][j] = fmaf(zv0.x, cv[j].x, a[0][j]);
                a[0][j] = fmaf(zv1.x, cv[j].y, a[0][j]);
                a[0][j] = fmaf(zv2.x, cv[j].z, a[0][j]);
                a[0][j] = fmaf(zv3.x, cv[j].w, a[0][j]);
                a[1][j] = fmaf(zv0.y, cv[j].x, a[1][j]);
                a[1][j] = fmaf(zv1.y, cv[j].y, a[1][j]);
                a[1][j] = fmaf(zv2.y, cv[j].z, a[1][j]);
                a[1][j] = fmaf(zv3.y, cv[j].w, a[1][j]);
                a[2][j] = fmaf(zv0.z, cv[j].x, a[2][j]);
                a[2][j] = fmaf(zv1.z, cv[j].y, a[2][j]);
                a[2][j] = fmaf(zv2.z, cv[j].z, a[2][j]);
                a[2][j] = fmaf(zv3.z, cv[j].w, a[2][j]);
                a[3][j] = fmaf(zv0.w, cv[j].x, a[3][j]);
                a[3][j] = fmaf(zv1.w, cv[j].y, a[3][j]);
                a[3][j] = fmaf(zv2.w, cv[j].z, a[3][j]);
                a[3][j] = fmaf(zv3.w, cv[j].w, a[3][j]);
            }
        }

        // d = fl(fl(z2 - 2*zc) + c2); strict < with ascending k
        #pragma unroll
        for (int j = 0; j < KT; ++j) {
            const float c2 = c2g[kb + j];
            #pragma unroll
            for (int i = 0; i < 4; ++i) {
                const float d = __fadd_rn(fmaf(-2.0f, a[i][j], z2r[i]), c2);
                if (d < bestd[i]) { bestd[i] = d; bestk[i] = kb + j; }
            }
        }
    }

    // ---- per-wave results: wave wid covers all 256 positions ---------------
    #pragma unroll
    for (int i = 0; i < 4; ++i) {
        bdls[wid][p0 + i] = bestd[i];
        bkls[wid][p0 + i] = (unsigned short)bestk[i];
    }
    __syncthreads();

    // ---- combine 16 disjoint code-strips per position; lexicographic (d,k)
    unsigned int* ghist = (unsigned int*)ws + WS_HIST;
    if (tid < P) {
        const int p = tid;
        float bd = bdls[0][p];
        int   bk = bkls[0][p];
        #pragma unroll
        for (int g = 1; g < NWAVES; ++g) {
            const float d = bdls[g][p];
            const int   k = bkls[g][p];
            if (d < bd || (d == bd && k < bk)) { bd = d; bk = k; }
        }
        wkls[p] = (unsigned short)bk;
        out[IDX_OFF + (size_t)(nbase + p)] = (float)bk;
        atomicAdd(&ghist[bk], 1u);       // 256/block, 1024 bins: low contention
        red[p] = bd;       // best_d == fl(||z-q||^2), loss has 2% slack
    }
    __syncthreads();
    for (int s = P / 2; s > 0; s >>= 1) {
        if (tid < s) red[tid] += red[tid + s];
        __syncthreads();
    }
    if (tid == 0) atomicAdd(&ws[WS_LOSS], red[0]);

    // ---- quantized output: out[b][c][hw0+p] = cb[wk[p]][c] -----------------
    // stores coalesced (1024B per c-row); cb gather L1/L2-hot.
    float* ob = out + (size_t)b * CDIM * HWSZ + hw0;
    #pragma unroll
    for (int i = 0; i < (CDIM * P) / THREADS; ++i) {   // 32 iters
        const int linear = i * THREADS + tid;          // 0..32767
        const int c = linear >> 8;
        const int p = linear & 255;
        ob[(size_t)c * HWSZ + p] = cb[(size_t)wkls[p] * CDIM + c];
    }
}

// ---- pass 2: scalars --------------------------------------------------------
__global__ __launch_bounds__(1024) void vq_final(const float* __restrict__ ws,
                                                 float* __restrict__ out) {
    __shared__ float red[1024];
    const int t = threadIdx.x;
    const unsigned int* hist = (const unsigned int*)ws + WS_HIST;
    const float p = (float)hist[t] * INV_NPOS;
    red[t] = p * logf(p + 1e-10f);
    __syncthreads();
    for (int s = 512; s > 0; s >>= 1) {
        if (t < s) red[t] += red[t + s];
        __syncthreads();
    }
    if (t == 0) {
        out[LOSS_OFF] = 1.25f * (ws[WS_LOSS] * INV_TOTAL);   // cb + 0.25*commit
        out[PERP_OFF] = expf(-red[0]);
    }
}

extern "C" void kernel_launch(void* const* d_in, const int* in_sizes, int n_in,
                              void* d_out, int out_size, void* d_ws, size_t ws_size,
                              hipStream_t stream) {
    const float* z  = (const float*)d_in[0];
    const float* cb = (const float*)d_in[1];
    float* out = (float*)d_out;
    float* ws  = (float*)d_ws;

    vq_prep <<<KCODES / 256, 256, 0, stream>>>(cb, ws);
    vq_main <<<NPOS / P,     THREADS, 0, stream>>>(z, cb, ws, out);
    vq_final<<<1,           1024, 0, stream>>>(ws, out);
}